// Round 8
// baseline (114.057 us; speedup 1.0000x reference)
//
#include <hip/hip_runtime.h>
#include <hip/hip_bf16.h>
#include <cstdint>
#include <cstddef>

#define NUM_CLASS 1000
#define NPAD      1024
#define LOW_DIM   128
#define B_UPD     1024
#define B_SIM     65536

typedef short bf16x8 __attribute__((ext_vector_type(8)));
typedef float f32x4  __attribute__((ext_vector_type(4)));

__device__ __forceinline__ unsigned short f2bf(float f) {
  union { float f; unsigned u; } a; a.f = f;
  unsigned u = a.u;
  return (unsigned short)((u + 0x7fffu + ((u >> 16) & 1u)) >> 16);  // RNE
}

// ---------- kernel 1: per-class EMA (ballot scan) + L2 norm -> fragment-swizzled bf16 ----------
// Updates to different labels commute, so per-class in-order processing
// reproduces the reference lax.scan exactly.
// Output layout = MFMA fragment order (per-lane data (idx=l&15, k=(l>>4)*8+e)):
//   slot[((g*4 + kk)*64 + l) * 8 + e]  (ushort units)
//   holds logical B[row = g*16 + (l&15)][k = kk*32 + (l>>4)*8 + e]
__global__ void proto_update_kernel(const float* __restrict__ pred_feat,
                                    const int*   __restrict__ labels,
                                    const float* __restrict__ protos_in,
                                    unsigned short* __restrict__ protos_sw) {
  int c = blockIdx.x;    // 0..1023
  int d = threadIdx.x;   // 0..127
  float p = 0.0f;
  if (c < NUM_CLASS) {
    p = protos_in[c * LOW_DIM + d];
    #pragma unroll 4
    for (int k = 0; k < B_UPD / 64; ++k) {
      int lab = labels[k * 64 + (d & 63)];
      unsigned long long m = __ballot(lab == c);   // wave-uniform
      while (m) {
        int b = __builtin_ctzll(m);
        m &= (m - 1);
        p = 0.99f * p + 0.01f * pred_feat[(size_t)(k * 64 + b) * LOW_DIM + d];
      }
    }
  }
  float sq = p * p;
  #pragma unroll
  for (int o = 1; o < 64; o <<= 1) sq += __shfl_xor(sq, o, 64);
  __shared__ float wsum[2];
  if ((d & 63) == 0) wsum[d >> 6] = sq;
  __syncthreads();
  float total = wsum[0] + wsum[1];
  unsigned short v = f2bf(p / fmaxf(sqrtf(total), 1e-12f));  // c>=1000 -> 0
  int g = c >> 4, r = c & 15, kk = d >> 5, j = (d >> 3) & 3, e = d & 7;
  protos_sw[(size_t)((g * 4 + kk) * 64 + j * 16 + r) * 8 + e] = v;
}

// ---------- kernel 2: C[65536,1000] = A(f32->bf16) @ B^T ----------
// SWAPPED-MFMA epilogue: D = mfma(proto_frag, feat_frag) puts row=class,
// col=feat-row, so reg r of lane l holds 4 CONSECUTIVE classes ->
// direct aligned f32x4 stores (16B/lane), no LDS transpose, no post-K barrier.
// BM=16, TPB=512, 8 waves; wave w owns all 16 rows x cols [w*128,(w+1)*128).
// acc[1][8]=32 VGPR -> launch_bounds(512,6) caps 85 VGPR -> 3 blocks/CU
// = 24 waves/CU (was 16). LDS = 4 KB. 4096 blocks x 64 KB contiguous output.
#define BM   16
#define TPB2 512

__global__ __launch_bounds__(TPB2, 6)
void gemm_sim_kernel(const float* __restrict__ A,
                     const unsigned short* __restrict__ Bsw,
                     float* __restrict__ C) {
  __shared__ alignas(16) unsigned char Als[BM * 256];   // 4 KB swizzled A
  int t  = threadIdx.x;
  int m0 = blockIdx.x * BM;

  // ---- stage A: 16 rows x 128 f32 -> bf16, XOR-swizzled (rows 256 B) ----
  // 512 threads x 4 f32: row = t>>5, quad c4 = t&31; 8B LDS write (XOR on
  // bit4 keeps 8B alignment).
  {
    int row = t >> 5, c4 = t & 31;
    float4 v = *reinterpret_cast<const float4*>(A + (size_t)(m0 + row) * LOW_DIM + c4 * 4);
    uint2 q;
    q.x = f2bf(v.x) | ((unsigned)f2bf(v.y) << 16);
    q.y = f2bf(v.z) | ((unsigned)f2bf(v.w) << 16);
    *reinterpret_cast<uint2*>(Als + row * 256 + ((c4 * 8) ^ ((row & 7) << 4))) = q;
  }
  __syncthreads();

  int lane = t & 63;
  int w    = t >> 6;
  int lr   = lane & 15;
  int lkb  = (lane >> 4) * 16;

  f32x4 acc[8];
  #pragma unroll
  for (int n = 0; n < 8; ++n)
    acc[n] = (f32x4){0.f, 0.f, 0.f, 0.f};

  #pragma unroll
  for (int kk = 0; kk < 4; ++kk) {             // K = 4 x 32
    int kb  = kk * 64 + lkb;
    int row = lr;
    bf16x8 af = *reinterpret_cast<const bf16x8*>(Als + row * 256 + (kb ^ ((row & 7) << 4)));
    #pragma unroll
    for (int n = 0; n < 8; ++n) {
      int g = w * 8 + n;                       // 16-class group
      bf16x8 bf = *reinterpret_cast<const bf16x8*>(
          Bsw + ((size_t)(g * 4 + kk) * 64 + lane) * 8);   // coalesced 1KB/wave
      // SWAPPED: proto fragment as a-operand -> D row = class, col = feat row
      acc[n] = __builtin_amdgcn_mfma_f32_16x16x32_bf16(bf, af, acc[n], 0, 0, 0);
    }
  }

  // ---- direct wide epilogue: reg r = 4 consecutive classes ----
  // lane l, group n: C[m0 + (l&15)][w*128 + n*16 + (l>>4)*4 + r], r=0..3.
  size_t rowoff = (size_t)(m0 + lr) * NUM_CLASS;
  int q = (lane >> 4) * 4;
  #pragma unroll
  for (int n = 0; n < 8; ++n) {
    int col = w * 128 + n * 16 + q;            // quad-aligned; 1000 % 4 == 0
    if (col < NUM_CLASS) {                     // only wave 7 n=6,7 partially masked
      *reinterpret_cast<f32x4*>(C + rowoff + col) = acc[n];
    }
  }
}

extern "C" void kernel_launch(void* const* d_in, const int* in_sizes, int n_in,
                              void* d_out, int out_size, void* d_ws, size_t ws_size,
                              hipStream_t stream) {
  const float* pred_feat = (const float*)d_in[0];   // [1024,128]
  const int*   labels    = (const int*)d_in[1];     // [1024]
  const float* protos    = (const float*)d_in[2];   // [1000,128]
  const float* feat      = (const float*)d_in[3];   // [65536,128]
  float* out = (float*)d_out;                       // [65536,1000]

  unsigned short* protos_sw = (unsigned short*)d_ws;  // 256 KB fragment-swizzled

  proto_update_kernel<<<NPAD, 128, 0, stream>>>(pred_feat, labels, protos, protos_sw);
  gemm_sim_kernel<<<B_SIM / BM, TPB2, 0, stream>>>(feat, protos_sw, out);
}

// Round 9
// 96.374 us; speedup vs baseline: 1.1835x; 1.1835x over previous
//
#include <hip/hip_runtime.h>
#include <hip/hip_bf16.h>
#include <cstdint>
#include <cstddef>

#define NUM_CLASS 1000
#define NPAD      1024
#define LOW_DIM   128
#define B_UPD     1024
#define B_SIM     65536

typedef short bf16x8 __attribute__((ext_vector_type(8)));
typedef float f32x4  __attribute__((ext_vector_type(4)));

__device__ __forceinline__ unsigned short f2bf(float f) {
  union { float f; unsigned u; } a; a.f = f;
  unsigned u = a.u;
  return (unsigned short)((u + 0x7fffu + ((u >> 16) & 1u)) >> 16);  // RNE
}

// ---------- kernel 1: per-class EMA (ballot scan) + L2 norm -> fragment-swizzled bf16 ----------
// Updates to different labels commute, so per-class in-order processing
// reproduces the reference lax.scan exactly.
// Output layout = MFMA A-operand fragment order (lane l: row=l&15, k=(l>>4)*8+e):
//   slot[((g*4 + kk)*64 + l) * 8 + e]  (ushort units)
//   holds logical B[row = g*16 + (l&15)][k = kk*32 + (l>>4)*8 + e]
__global__ void proto_update_kernel(const float* __restrict__ pred_feat,
                                    const int*   __restrict__ labels,
                                    const float* __restrict__ protos_in,
                                    unsigned short* __restrict__ protos_sw) {
  int c = blockIdx.x;    // 0..1023
  int d = threadIdx.x;   // 0..127
  float p = 0.0f;
  if (c < NUM_CLASS) {
    p = protos_in[c * LOW_DIM + d];
    #pragma unroll 4
    for (int k = 0; k < B_UPD / 64; ++k) {
      int lab = labels[k * 64 + (d & 63)];
      unsigned long long m = __ballot(lab == c);   // wave-uniform
      while (m) {
        int b = __builtin_ctzll(m);
        m &= (m - 1);
        p = 0.99f * p + 0.01f * pred_feat[(size_t)(k * 64 + b) * LOW_DIM + d];
      }
    }
  }
  float sq = p * p;
  #pragma unroll
  for (int o = 1; o < 64; o <<= 1) sq += __shfl_xor(sq, o, 64);
  __shared__ float wsum[2];
  if ((d & 63) == 0) wsum[d >> 6] = sq;
  __syncthreads();
  float total = wsum[0] + wsum[1];
  unsigned short v = f2bf(p / fmaxf(sqrtf(total), 1e-12f));  // c>=1000 -> 0
  int g = c >> 4, r = c & 15, kk = d >> 5, j = (d >> 3) & 3, e = d & 7;
  protos_sw[(size_t)((g * 4 + kk) * 64 + j * 16 + r) * 8 + e] = v;
}

// ---------- kernel 2: C[65536,1000] = A(f32->bf16) @ B^T, BM=32 x full-N ----------
// R6 geometry (BM=32, TPB=512, 8 waves, acc[2][8], 2:1 MFMA:B-load) with the
// SWAPPED-MFMA direct epilogue (HW-verified in R8): D = mfma(proto_frag,
// feat_frag) -> D row = class, col = feat row; reg quad = 4 consecutive
// classes -> aligned f32x4 stores straight from acc. No post-K barrier, no
// epilogue LDS (LDS 67.6 KB -> 8 KB), stores stay 16 B/lane; the 8 n-stores
// complete 512 B per output row so L2 write-combining preserves R6's burst
// pattern. Wave w owns 32 feat rows x classes [w*128, w*128+128).
#define BM   32
#define TPB2 512

__global__ __launch_bounds__(TPB2, 4)
void gemm_sim_kernel(const float* __restrict__ A,
                     const unsigned short* __restrict__ Bsw,
                     float* __restrict__ C) {
  __shared__ alignas(16) unsigned char Als[BM * 256];   // 8 KB swizzled A
  int t  = threadIdx.x;
  int m0 = blockIdx.x * BM;

  // ---- stage A: exactly 32 rows x 128 f32 -> bf16, XOR-swizzled (rows 256 B) ----
  {
    int row = t >> 4, c8 = t & 15;   // 512 threads = 32 rows x 16 slots
    const float4* s = reinterpret_cast<const float4*>(A + (size_t)(m0 + row) * LOW_DIM + c8 * 8);
    float4 v0 = s[0], v1 = s[1];
    uint4 q;
    q.x = f2bf(v0.x) | ((unsigned)f2bf(v0.y) << 16);
    q.y = f2bf(v0.z) | ((unsigned)f2bf(v0.w) << 16);
    q.z = f2bf(v1.x) | ((unsigned)f2bf(v1.y) << 16);
    q.w = f2bf(v1.z) | ((unsigned)f2bf(v1.w) << 16);
    *reinterpret_cast<uint4*>(Als + row * 256 + ((c8 * 16) ^ ((row & 7) << 4))) = q;
  }
  __syncthreads();

  int lane = t & 63;
  int w    = t >> 6;
  int lr   = lane & 15;
  int lkb  = (lane >> 4) * 16;

  f32x4 acc[2][8];
  #pragma unroll
  for (int m = 0; m < 2; ++m)
    #pragma unroll
    for (int n = 0; n < 8; ++n)
      acc[m][n] = (f32x4){0.f, 0.f, 0.f, 0.f};

  #pragma unroll
  for (int kk = 0; kk < 4; ++kk) {             // K = 4 x 32
    int kb = kk * 64 + lkb;
    bf16x8 af[2];
    #pragma unroll
    for (int m = 0; m < 2; ++m) {
      int row = m * 16 + lr;
      af[m] = *reinterpret_cast<const bf16x8*>(Als + row * 256 + (kb ^ ((row & 7) << 4)));
    }
    #pragma unroll
    for (int n = 0; n < 8; ++n) {
      int g = w * 8 + n;                       // 16-class group
      bf16x8 bf = *reinterpret_cast<const bf16x8*>(
          Bsw + ((size_t)(g * 4 + kk) * 64 + lane) * 8);   // coalesced 1KB/wave
      #pragma unroll
      for (int m = 0; m < 2; ++m)
        // SWAPPED: proto fragment is the a-operand -> D row=class, col=feat row
        acc[m][n] = __builtin_amdgcn_mfma_f32_16x16x32_bf16(bf, af[m], acc[m][n], 0, 0, 0);
    }
  }

  // ---- direct wide epilogue: reg quad = 4 consecutive classes ----
  // acc[m][n], lane l: C[m0 + m*16 + (l&15)][w*128 + n*16 + (l>>4)*4 + r]
  int q = (lane >> 4) * 4;
  #pragma unroll
  for (int m = 0; m < 2; ++m) {
    size_t rowoff = (size_t)(m0 + m * 16 + lr) * NUM_CLASS;
    #pragma unroll
    for (int n = 0; n < 8; ++n) {
      int col = w * 128 + n * 16 + q;          // multiple of 4; 1000 % 4 == 0
      if (col < NUM_CLASS) {                   // only wave 7's n=6,7 tail masked
        *reinterpret_cast<f32x4*>(C + rowoff + col) = acc[m][n];
      }
    }
  }
}

extern "C" void kernel_launch(void* const* d_in, const int* in_sizes, int n_in,
                              void* d_out, int out_size, void* d_ws, size_t ws_size,
                              hipStream_t stream) {
  const float* pred_feat = (const float*)d_in[0];   // [1024,128]
  const int*   labels    = (const int*)d_in[1];     // [1024]
  const float* protos    = (const float*)d_in[2];   // [1000,128]
  const float* feat      = (const float*)d_in[3];   // [65536,128]
  float* out = (float*)d_out;                       // [65536,1000]

  unsigned short* protos_sw = (unsigned short*)d_ws;  // 256 KB fragment-swizzled

  proto_update_kernel<<<NPAD, 128, 0, stream>>>(pred_feat, labels, protos, protos_sw);
  gemm_sim_kernel<<<B_SIM / BM, TPB2, 0, stream>>>(feat, protos_sw, out);
}